// Round 4
// baseline (1712.503 us; speedup 1.0000x reference)
//
#include <hip/hip_runtime.h>

#define B 512
#define L 1024
#define T 128
#define NROWS (L - 1)   /* 1023 */
#define SEG 64
#define NSEG 16

typedef unsigned char u8;
typedef float f2 __attribute__((ext_vector_type(2)));

#if __has_builtin(__builtin_elementwise_max)
#define MAX2(a, b) __builtin_elementwise_max((a), (b))
#else
static __device__ __forceinline__ f2 max2_(f2 a, f2 b) {
    f2 r; r.x = fmaxf(a.x, b.x); r.y = fmaxf(a.y, b.y); return r;
}
#define MAX2(a, b) max2_((a), (b))
#endif
#define M3(a, b, c) fmaxf(fmaxf((a), (b)), (c))

// barrier WITHOUT vmcnt(0) drain: LDS visibility only (m201-verified pattern).
#define BAR()                                                  \
    do {                                                       \
        asm volatile("s_waitcnt lgkmcnt(0)" ::: "memory");     \
        __builtin_amdgcn_s_barrier();                          \
        asm volatile("" ::: "memory");                         \
    } while (0)

// ===========================================================================
// FAST PATH (needs ~268 MB workspace)
// ===========================================================================

// ---------------------------------------------------------------------------
// Forward, VALUES ONLY. 512 thr: h=tid&3 (i-quarter), j=tid>>2 (tag).
// Exact: s = (prev[i] + obs[j]) + trans[i][j]; max via pk_max tree (assoc-safe).
// Stores every prev row (f32 exact) to ws; stores deferred 1 step (no drain).
// ---------------------------------------------------------------------------
__global__ __launch_bounds__(512, 4) void viterbi_fwd_val(
    const float* __restrict__ emit, const float* __restrict__ trans,
    const float* __restrict__ w, float* __restrict__ out,
    float* __restrict__ prevws, int* __restrict__ lastTag)
{
    const int b   = blockIdx.x;
    const int tid = threadIdx.x;
    const int h   = tid & 3;
    const int j   = tid >> 2;
    const int hbase = h << 5;
    const bool lane0 = (h == 0);

    __shared__ __align__(16) float prevbuf[2 * T];
    __shared__ float swv[8];
    __shared__ int   swj[8];

    f2 tc2[16];
#pragma unroll
    for (int q = 0; q < 8; ++q) {
        f2 a, c;
        a.x = trans[(size_t)(hbase + 4 * q + 0) * T + j];
        a.y = trans[(size_t)(hbase + 4 * q + 1) * T + j];
        c.x = trans[(size_t)(hbase + 4 * q + 2) * T + j];
        c.y = trans[(size_t)(hbase + 4 * q + 3) * T + j];
        tc2[2 * q] = a; tc2[2 * q + 1] = c;
    }

    const float wj = w[j];
    const size_t ebase = (size_t)b * L * T;
    float* prow = prevws + (size_t)b * NROWS * T;

    const char* prd = (const char*)prevbuf + 128 * h;
    char* pwr = (char*)prevbuf + 16 * ((j >> 2) ^ (j >> 5)) + 4 * (j & 3);

    // t=0 init
    const float e0 = emit[ebase + j] * wj;
    if (lane0) *(float*)pwr = e0;
    if (h == 1) prow[j] = e0;                       // prev row 0
    float myprev = e0;
    // emit prefetch, depth 2
    float r_c = emit[ebase + (size_t)T + j];        // row 1
    float r_1 = emit[ebase + (size_t)2 * T + j];    // row 2
    float bv_prev = 0.0f;
    BAR();

#define STEP(T_, ROFF_, WOFF_)                                                 \
    {                                                                          \
        const int t_ = (T_);                                                   \
        if (h == 1 && t_ >= 2)                       /* deferred prev store */ \
            prow[(size_t)(t_ - 1) * T + j] = bv_prev;                          \
        const int tn_ = (t_ + 2 < L) ? (t_ + 2) : (L - 1);                     \
        const float r_2 = emit[ebase + (size_t)tn_ * T + j];                   \
        const float obs_ = r_c * wj;                                           \
        f2 od_; od_.x = obs_; od_.y = obs_;                                    \
        f2 sv[16];                                                             \
        _Pragma("unroll")                                                      \
        for (int q = 0; q < 8; ++q) {                                          \
            const float4 p = *(const float4*)(prd + (ROFF_) + 16 * (q ^ h));   \
            f2 plo; plo.x = p.x; plo.y = p.y;                                  \
            f2 phi; phi.x = p.z; phi.y = p.w;                                  \
            sv[2 * q]     = (plo + od_) + tc2[2 * q];                          \
            sv[2 * q + 1] = (phi + od_) + tc2[2 * q + 1];                      \
        }                                                                      \
        const f2 a0 = MAX2(sv[0], sv[1]),   a1 = MAX2(sv[2], sv[3]);           \
        const f2 a2 = MAX2(sv[4], sv[5]),   a3 = MAX2(sv[6], sv[7]);           \
        const f2 a4 = MAX2(sv[8], sv[9]),   a5 = MAX2(sv[10], sv[11]);         \
        const f2 a6 = MAX2(sv[12], sv[13]), a7 = MAX2(sv[14], sv[15]);         \
        const f2 b0 = MAX2(a0, a1), b1 = MAX2(a2, a3);                         \
        const f2 b2 = MAX2(a4, a5), b3 = MAX2(a6, a7);                         \
        const f2 c0 = MAX2(b0, b1), c1 = MAX2(b2, b3);                         \
        const f2 d0 = MAX2(c0, c1);                                            \
        float bv = fmaxf(d0.x, d0.y);                                          \
        bv = fmaxf(bv, __shfl_xor(bv, 1));                                     \
        bv = fmaxf(bv, __shfl_xor(bv, 2));                                     \
        if (lane0) *(float*)(pwr + (WOFF_)) = bv;                              \
        myprev = bv;                                                           \
        bv_prev = bv;                                                          \
        r_c = r_1; r_1 = r_2;                                                  \
        BAR();                                                                 \
    }

    int t = 1;
    while (t + 1 < L) {
        STEP(t, 0, 512)
        STEP(t + 1, 512, 0)
        t += 2;
    }
    STEP(1023, 0, 512)
#undef STEP
    // prev_1022 store (deferred from step 1023's bottom would be 1023; row
    // 1022 was stored at step 1023's top). Rows 0..1022 all covered.

    // final reduce: best_score + last tag (first-occurrence argmax)
    float rv = myprev; int rj = j;
#pragma unroll
    for (int m = 4; m <= 32; m <<= 1) {
        const float pv = __shfl_xor(rv, m);
        const int   pj = __shfl_xor(rj, m);
        if (pv > rv || (pv == rv && pj < rj)) { rv = pv; rj = pj; }
    }
    if ((tid & 63) == 0) { swv[tid >> 6] = rv; swj[tid >> 6] = rj; }
    __syncthreads();
    if (tid == 0) {
        float fv = swv[0]; int fj = swj[0];
#pragma unroll
        for (int wv = 1; wv < 8; ++wv) {
            if (swv[wv] > fv || (swv[wv] == fv && swj[wv] < fj)) {
                fv = swv[wv]; fj = swj[wv];
            }
        }
        out[(size_t)B * L + b] = fv;
        out[(size_t)b * L + (L - 1)] = (float)fj;
        lastTag[b] = fj;
    }
}

// ---------------------------------------------------------------------------
// Backtrace: 1 wave per batch. Recomputes argmax ONLY along the path.
// transT staged in LDS with XOR swizzle (conflict-free); prev/emit rows
// prefetched one step ahead (addresses path-independent); obs via __shfl.
// ---------------------------------------------------------------------------
__global__ __launch_bounds__(64, 1) void backtrace(
    const float* __restrict__ emit, const float* __restrict__ trans,
    const float* __restrict__ w, const float* __restrict__ prevws,
    const int* __restrict__ lastTag, float* __restrict__ out)
{
    const int b = blockIdx.x;
    const int lane = threadIdx.x;
    __shared__ float transT[T * T];   // 64 KB

    // stage transposed: transT[j][i ^ (j&31)] = trans[i][j]
#pragma unroll 4
    for (int it = 0; it < (T * T) / 64; ++it) {
        const int k = it * 64 + lane;
        const int i = k >> 7, jj = k & 127;
        transT[jj * T + (i ^ (jj & 31))] = trans[k];
    }
    __syncthreads();

    const float w0 = w[lane], w1 = w[lane + 64];
    int idx = lastTag[b];

    const size_t pb0 = ((size_t)b * NROWS + 1022) * T;
    float pv0 = prevws[pb0 + lane], pv1 = prevws[pb0 + lane + 64];
    const size_t eb0 = ((size_t)b * L + 1023) * T;
    float raw0 = emit[eb0 + lane], raw1 = emit[eb0 + lane + 64];

    for (int r = 1022; r >= 0; --r) {
        float npv0 = 0.f, npv1 = 0.f, nr0 = 0.f, nr1 = 0.f;
        if (r > 0) {   // prefetch rows for step r-1
            const size_t pb = ((size_t)b * NROWS + (r - 1)) * T;
            npv0 = prevws[pb + lane]; npv1 = prevws[pb + lane + 64];
            const size_t eb = ((size_t)b * L + r) * T;
            nr0 = emit[eb + lane]; nr1 = emit[eb + lane + 64];
        }
        const int c = idx & 31;
        const float c0 = transT[idx * T + (lane ^ c)];          // trans[lane][idx]
        const float c1 = transT[idx * T + ((lane + 64) ^ c)];   // trans[lane+64][idx]
        const float ew0 = raw0 * w0, ew1 = raw1 * w1;
        const float obs = __shfl((idx < 64) ? ew0 : ew1, idx & 63);
        const float s0 = (pv0 + obs) + c0;
        const float s1 = (pv1 + obs) + c1;
        float v = s0; int vi = lane;
        if (s1 > v) { v = s1; vi = lane + 64; }   // tie -> lane (smaller) ✓
#pragma unroll
        for (int m = 1; m <= 32; m <<= 1) {
            const float pv = __shfl_xor(v, m);
            const int   pi = __shfl_xor(vi, m);
            if (pv > v || (pv == v && pi < vi)) { v = pv; vi = pi; }
        }
        idx = vi;
        if (lane == 0) out[(size_t)b * L + r] = (float)idx;
        pv0 = npv0; pv1 = npv1; raw0 = nr0; raw1 = nr1;
    }
}

// ===========================================================================
// FALLBACK PATH (R3 kernels, used when ws_size < 268 MB)
// ===========================================================================
__global__ __launch_bounds__(512, 4) void viterbi_fwd_slow(
    const float* __restrict__ emit, const float* __restrict__ trans,
    const float* __restrict__ w, float* __restrict__ out,
    u8* __restrict__ bps, int* __restrict__ lastTag)
{
    const int b   = blockIdx.x;
    const int tid = threadIdx.x;
    const int h   = tid & 3;
    const int j   = tid >> 2;
    const int hbase = h << 5;
    const bool lane0 = (h == 0);
    const int INF = 0x7fffffff;

    __shared__ __align__(16) float prevbuf[2 * T];
    __shared__ float swv[8];
    __shared__ int   swj[8];

    f2 tc2[16];
#pragma unroll
    for (int q = 0; q < 8; ++q) {
        f2 a, c;
        a.x = trans[(size_t)(hbase + 4 * q + 0) * T + j];
        a.y = trans[(size_t)(hbase + 4 * q + 1) * T + j];
        c.x = trans[(size_t)(hbase + 4 * q + 2) * T + j];
        c.y = trans[(size_t)(hbase + 4 * q + 3) * T + j];
        tc2[2 * q] = a; tc2[2 * q + 1] = c;
    }

    const float wj = w[j];
    const size_t ebase = (size_t)b * L * T;
    u8* bprow = bps + (size_t)b * NROWS * T;

    const char* prd = (const char*)prevbuf + 128 * h;
    char* pwr = (char*)prevbuf + 16 * ((j >> 2) ^ (j >> 5)) + 4 * (j & 3);

    const float e0 = emit[ebase + j] * wj;
    if (lane0) *(float*)pwr = e0;
    float myprev = e0;
    float raw_cur = emit[ebase + (size_t)T + j];
    int bidx_prev = 0;
    __syncthreads();

#define STEP(T_, ROFF_, WOFF_)                                                 \
    {                                                                          \
        const int t_ = (T_);                                                   \
        if (lane0 && t_ >= 2)                                                  \
            bprow[(size_t)(t_ - 2) * T + j] = (u8)bidx_prev;                   \
        const int tn_ = (t_ + 1 < L) ? (t_ + 1) : (L - 1);                     \
        const float raw_next_ = emit[ebase + (size_t)tn_ * T + j];             \
        const float obs_ = raw_cur * wj;                                       \
        f2 od_; od_.x = obs_; od_.y = obs_;                                    \
        f2 sv[16];                                                             \
        _Pragma("unroll")                                                      \
        for (int q = 0; q < 8; ++q) {                                          \
            const float4 p = *(const float4*)(prd + (ROFF_) + 16 * (q ^ h));   \
            f2 plo; plo.x = p.x; plo.y = p.y;                                  \
            f2 phi; phi.x = p.z; phi.y = p.w;                                  \
            sv[2 * q]     = (plo + od_) + tc2[2 * q];                          \
            sv[2 * q + 1] = (phi + od_) + tc2[2 * q + 1];                      \
        }                                                                      \
        float cm[4]; int loc[4];                                               \
        _Pragma("unroll")                                                      \
        for (int c = 0; c < 4; ++c) {                                          \
            const float s0 = sv[4 * c + 0].x, s1 = sv[4 * c + 0].y;            \
            const float s2 = sv[4 * c + 1].x, s3 = sv[4 * c + 1].y;            \
            const float s4 = sv[4 * c + 2].x, s5 = sv[4 * c + 2].y;            \
            const float s6 = sv[4 * c + 3].x, s7 = sv[4 * c + 3].y;            \
            const float m = M3(M3(s0, s1, s2), M3(s3, s4, s5),                 \
                               fmaxf(s6, s7));                                 \
            int k = 0;                                                         \
            k = (s7 == m) ? 7 : k; k = (s6 == m) ? 6 : k;                      \
            k = (s5 == m) ? 5 : k; k = (s4 == m) ? 4 : k;                      \
            k = (s3 == m) ? 3 : k; k = (s2 == m) ? 2 : k;                      \
            k = (s1 == m) ? 1 : k;                                             \
            cm[c] = m; loc[c] = 8 * c + k;                                     \
        }                                                                      \
        float bv = fmaxf(fmaxf(cm[0], cm[1]), fmaxf(cm[2], cm[3]));            \
        const int l0 = (cm[0] == bv) ? loc[0] : INF;                           \
        const int l1 = (cm[1] == bv) ? loc[1] : INF;                           \
        const int l2 = (cm[2] == bv) ? loc[2] : INF;                           \
        const int l3 = (cm[3] == bv) ? loc[3] : INF;                           \
        const int lm = min(min(min(l0, l1), l2), l3);                          \
        int gi = hbase + lm;                                                   \
        const float lv = bv;                                                   \
        bv = fmaxf(bv, __shfl_xor(bv, 1));                                     \
        bv = fmaxf(bv, __shfl_xor(bv, 2));                                     \
        int ii = (lv == bv) ? gi : INF;                                        \
        ii = min(ii, __shfl_xor(ii, 1));                                       \
        ii = min(ii, __shfl_xor(ii, 2));                                       \
        if (lane0) *(float*)(pwr + (WOFF_)) = bv;                              \
        myprev = bv;                                                           \
        bidx_prev = ii;                                                        \
        raw_cur = raw_next_;                                                   \
        __syncthreads();                                                       \
    }

    int t = 1;
    while (t + 1 < L) {
        STEP(t, 0, 512)
        STEP(t + 1, 512, 0)
        t += 2;
    }
    STEP(1023, 0, 512)
#undef STEP

    if (lane0) bprow[(size_t)(NROWS - 1) * T + j] = (u8)bidx_prev;

    float rv = myprev; int rj = j;
#pragma unroll
    for (int m = 4; m <= 32; m <<= 1) {
        const float pv = __shfl_xor(rv, m);
        const int   pj = __shfl_xor(rj, m);
        if (pv > rv || (pv == rv && pj < rj)) { rv = pv; rj = pj; }
    }
    if ((tid & 63) == 0) { swv[tid >> 6] = rv; swj[tid >> 6] = rj; }
    __syncthreads();
    if (tid == 0) {
        float fv = swv[0]; int fj = swj[0];
#pragma unroll
        for (int wv = 1; wv < 8; ++wv) {
            if (swv[wv] > fv || (swv[wv] == fv && swj[wv] < fj)) {
                fv = swv[wv]; fj = swj[wv];
            }
        }
        out[(size_t)B * L + b] = fv;
        out[(size_t)b * L + (L - 1)] = (float)fj;
        lastTag[b] = fj;
    }
}

__global__ __launch_bounds__(T) void segcomp(const u8* __restrict__ bps,
                                             u8* __restrict__ comp)
{
    const int s = blockIdx.x & (NSEG - 1);
    const int b = blockIdx.x >> 4;
    const int r0 = s * SEG;
    const int cnt = (NROWS - r0 < SEG) ? (NROWS - r0) : SEG;

    __shared__ __align__(16) u8 rows[SEG * T];
    const uint4* src = (const uint4*)(bps + ((size_t)b * NROWS + r0) * T);
    uint4* dst = (uint4*)rows;
    const int nvec = cnt * (T / 16);
    for (int k = threadIdx.x; k < nvec; k += T) dst[k] = src[k];
    __syncthreads();

    int x = threadIdx.x;
    for (int k = cnt - 1; k >= 0; --k) x = rows[k * T + x];
    comp[((size_t)b * NSEG + s) * T + threadIdx.x] = (u8)x;
}

__global__ void chainseg(const u8* __restrict__ comp,
                         const int* __restrict__ lastTag,
                         float* __restrict__ out)
{
    const int b = blockIdx.x * blockDim.x + threadIdx.x;
    if (b >= B) return;
    int e = lastTag[b];
#pragma unroll 1
    for (int s = NSEG - 1; s >= 0; --s) {
        e = comp[((size_t)b * NSEG + s) * T + e];
        out[(size_t)b * L + s * SEG] = (float)e;
    }
}

__global__ __launch_bounds__(T) void fillseg(const u8* __restrict__ bps,
                                             const int* __restrict__ lastTag,
                                             float* __restrict__ out)
{
    const int s = blockIdx.x & (NSEG - 1);
    const int b = blockIdx.x >> 4;
    const int r0 = s * SEG;
    const int cnt = (NROWS - r0 < SEG) ? (NROWS - r0) : SEG;

    __shared__ __align__(16) u8 rows[SEG * T];
    const uint4* src = (const uint4*)(bps + ((size_t)b * NROWS + r0) * T);
    uint4* dst = (uint4*)rows;
    const int nvec = cnt * (T / 16);
    for (int k = threadIdx.x; k < nvec; k += T) dst[k] = src[k];
    __syncthreads();

    if (threadIdx.x == 0) {
        int e = (s == NSEG - 1) ? lastTag[b]
                                : (int)out[(size_t)b * L + (size_t)(s + 1) * SEG];
        for (int k = cnt - 1; k >= 1; --k) {
            e = rows[k * T + e];
            out[(size_t)b * L + r0 + k] = (float)e;
        }
    }
}

// ---------------------------------------------------------------------------
extern "C" void kernel_launch(void* const* d_in, const int* in_sizes, int n_in,
                              void* d_out, int out_size, void* d_ws, size_t ws_size,
                              hipStream_t stream)
{
    const float* emit  = (const float*)d_in[0];
    const float* trans = (const float*)d_in[1];
    const float* w     = (const float*)d_in[2];
    float* out = (float*)d_out;

    const size_t prev_bytes = (size_t)B * NROWS * T * sizeof(float); // 268 MB
    const size_t need_fast  = prev_bytes + B * sizeof(int);

    if (ws_size >= need_fast) {
        float* prevws  = (float*)d_ws;
        int*   lastTag = (int*)((char*)d_ws + prev_bytes);
        viterbi_fwd_val<<<B, 512, 0, stream>>>(emit, trans, w, out, prevws, lastTag);
        backtrace<<<B, 64, 0, stream>>>(emit, trans, w, prevws, lastTag, out);
    } else {
        u8*  bps     = (u8*)d_ws;
        u8*  comp    = bps + (size_t)B * NROWS * T;
        int* lastTag = (int*)(comp + (size_t)B * NSEG * T);
        viterbi_fwd_slow<<<B, 512, 0, stream>>>(emit, trans, w, out, bps, lastTag);
        segcomp<<<B * NSEG, T, 0, stream>>>(bps, comp);
        chainseg<<<2, 256, 0, stream>>>(comp, lastTag, out);
        fillseg<<<B * NSEG, T, 0, stream>>>(bps, lastTag, out);
    }
}

// Round 5
// 877.654 us; speedup vs baseline: 1.9512x; 1.9512x over previous
//
#include <hip/hip_runtime.h>

#define B 512
#define L 1024
#define T 128
#define NROWS (L - 1)   /* 1023 */
#define SEG 64
#define NSEG 16

typedef unsigned char u8;
typedef float f2 __attribute__((ext_vector_type(2)));

#if __has_builtin(__builtin_elementwise_max)
#define MAX2(a, b) __builtin_elementwise_max((a), (b))
#else
static __device__ __forceinline__ f2 max2_(f2 a, f2 b) {
    f2 r; r.x = fmaxf(a.x, b.x); r.y = fmaxf(a.y, b.y); return r;
}
#define MAX2(a, b) max2_((a), (b))
#endif
#define M3(a, b, c) fmaxf(fmaxf((a), (b)), (c))

// barrier WITHOUT vmcnt(0) drain: LDS visibility only (m201-verified pattern).
#define BAR()                                                  \
    do {                                                       \
        asm volatile("s_waitcnt lgkmcnt(0)" ::: "memory");     \
        __builtin_amdgcn_s_barrier();                          \
        asm volatile("" ::: "memory");                         \
    } while (0)

// ===========================================================================
// FAST PATH (needs ~268 MB workspace)
// ===========================================================================

// ---------------------------------------------------------------------------
// Forward, VALUES ONLY (unchanged from R4 — bitwise-proven).
// ---------------------------------------------------------------------------
__global__ __launch_bounds__(512, 4) void viterbi_fwd_val(
    const float* __restrict__ emit, const float* __restrict__ trans,
    const float* __restrict__ w, float* __restrict__ out,
    float* __restrict__ prevws, int* __restrict__ lastTag)
{
    const int b   = blockIdx.x;
    const int tid = threadIdx.x;
    const int h   = tid & 3;
    const int j   = tid >> 2;
    const int hbase = h << 5;
    const bool lane0 = (h == 0);

    __shared__ __align__(16) float prevbuf[2 * T];
    __shared__ float swv[8];
    __shared__ int   swj[8];

    f2 tc2[16];
#pragma unroll
    for (int q = 0; q < 8; ++q) {
        f2 a, c;
        a.x = trans[(size_t)(hbase + 4 * q + 0) * T + j];
        a.y = trans[(size_t)(hbase + 4 * q + 1) * T + j];
        c.x = trans[(size_t)(hbase + 4 * q + 2) * T + j];
        c.y = trans[(size_t)(hbase + 4 * q + 3) * T + j];
        tc2[2 * q] = a; tc2[2 * q + 1] = c;
    }

    const float wj = w[j];
    const size_t ebase = (size_t)b * L * T;
    float* prow = prevws + (size_t)b * NROWS * T;

    const char* prd = (const char*)prevbuf + 128 * h;
    char* pwr = (char*)prevbuf + 16 * ((j >> 2) ^ (j >> 5)) + 4 * (j & 3);

    const float e0 = emit[ebase + j] * wj;
    if (lane0) *(float*)pwr = e0;
    if (h == 1) prow[j] = e0;                       // prev row 0
    float myprev = e0;
    float r_c = emit[ebase + (size_t)T + j];        // row 1
    float r_1 = emit[ebase + (size_t)2 * T + j];    // row 2
    float bv_prev = 0.0f;
    BAR();

#define STEP(T_, ROFF_, WOFF_)                                                 \
    {                                                                          \
        const int t_ = (T_);                                                   \
        if (h == 1 && t_ >= 2)                                                 \
            prow[(size_t)(t_ - 1) * T + j] = bv_prev;                          \
        const int tn_ = (t_ + 2 < L) ? (t_ + 2) : (L - 1);                     \
        const float r_2 = emit[ebase + (size_t)tn_ * T + j];                   \
        const float obs_ = r_c * wj;                                           \
        f2 od_; od_.x = obs_; od_.y = obs_;                                    \
        f2 sv[16];                                                             \
        _Pragma("unroll")                                                      \
        for (int q = 0; q < 8; ++q) {                                          \
            const float4 p = *(const float4*)(prd + (ROFF_) + 16 * (q ^ h));   \
            f2 plo; plo.x = p.x; plo.y = p.y;                                  \
            f2 phi; phi.x = p.z; phi.y = p.w;                                  \
            sv[2 * q]     = (plo + od_) + tc2[2 * q];                          \
            sv[2 * q + 1] = (phi + od_) + tc2[2 * q + 1];                      \
        }                                                                      \
        const f2 a0 = MAX2(sv[0], sv[1]),   a1 = MAX2(sv[2], sv[3]);           \
        const f2 a2 = MAX2(sv[4], sv[5]),   a3 = MAX2(sv[6], sv[7]);           \
        const f2 a4 = MAX2(sv[8], sv[9]),   a5 = MAX2(sv[10], sv[11]);         \
        const f2 a6 = MAX2(sv[12], sv[13]), a7 = MAX2(sv[14], sv[15]);         \
        const f2 b0 = MAX2(a0, a1), b1 = MAX2(a2, a3);                         \
        const f2 b2 = MAX2(a4, a5), b3 = MAX2(a6, a7);                         \
        const f2 c0 = MAX2(b0, b1), c1 = MAX2(b2, b3);                         \
        const f2 d0 = MAX2(c0, c1);                                            \
        float bv = fmaxf(d0.x, d0.y);                                          \
        bv = fmaxf(bv, __shfl_xor(bv, 1));                                     \
        bv = fmaxf(bv, __shfl_xor(bv, 2));                                     \
        if (lane0) *(float*)(pwr + (WOFF_)) = bv;                              \
        myprev = bv;                                                           \
        bv_prev = bv;                                                          \
        r_c = r_1; r_1 = r_2;                                                  \
        BAR();                                                                 \
    }

    int t = 1;
    while (t + 1 < L) {
        STEP(t, 0, 512)
        STEP(t + 1, 512, 0)
        t += 2;
    }
    STEP(1023, 0, 512)
#undef STEP

    float rv = myprev; int rj = j;
#pragma unroll
    for (int m = 4; m <= 32; m <<= 1) {
        const float pv = __shfl_xor(rv, m);
        const int   pj = __shfl_xor(rj, m);
        if (pv > rv || (pv == rv && pj < rj)) { rv = pv; rj = pj; }
    }
    if ((tid & 63) == 0) { swv[tid >> 6] = rv; swj[tid >> 6] = rj; }
    __syncthreads();
    if (tid == 0) {
        float fv = swv[0]; int fj = swj[0];
#pragma unroll
        for (int wv = 1; wv < 8; ++wv) {
            if (swv[wv] > fv || (swv[wv] == fv && swj[wv] < fj)) {
                fv = swv[wv]; fj = swj[wv];
            }
        }
        out[(size_t)B * L + b] = fv;
        out[(size_t)b * L + (L - 1)] = (float)fj;
        lastTag[b] = fj;
    }
}

// ---------------------------------------------------------------------------
// Backtrace v2: ballot-based, no max reduce.
// Invariant: prevws[t][idx] is BITWISE the max of the candidate set
// {(prevws[t-1][i] + obs_t) + trans[i][idx]} (fwd computed it that way).
// So: recompute s_i with identical op order, find FIRST i with s_i == bv
// via __ballot + ctz (i<64 half checked before i>=64 → first-occurrence).
// 8-deep register-ring prefetch of prevws/emit rows (compile-time indices).
// ---------------------------------------------------------------------------
__global__ __launch_bounds__(64, 1) void backtrace(
    const float* __restrict__ emit, const float* __restrict__ trans,
    const float* __restrict__ w, const float* __restrict__ prevws,
    const int* __restrict__ lastTag, float* __restrict__ out)
{
    const int b = blockIdx.x;
    const int lane = threadIdx.x;
    __shared__ float transT[T * T];   // 64 KB

    // stage transposed + swizzled: transT[j][i ^ (j&31)] = trans[i][j]
#pragma unroll 4
    for (int it = 0; it < (T * T) / 64; ++it) {
        const int k = it * 64 + lane;
        const int i = k >> 7, jj = k & 127;
        transT[jj * T + (i ^ (jj & 31))] = trans[k];
    }

    const float w0 = w[lane], w1 = w[lane + 64];
    const size_t pbase = (size_t)b * NROWS * T;
    const size_t ebase = (size_t)b * L * T;
    const size_t obase = (size_t)b * L;

    // 8-deep ring: rp = prevws row r, re = raw emit row r+1
    float rp0[8], rp1[8], re0[8], re1[8];
#pragma unroll
    for (int k = 0; k < 8; ++k) {
        rp0[k] = prevws[pbase + (size_t)(1022 - k) * T + lane];
        rp1[k] = prevws[pbase + (size_t)(1022 - k) * T + lane + 64];
        re0[k] = emit[ebase + (size_t)(1023 - k) * T + lane];
        re1[k] = emit[ebase + (size_t)(1023 - k) * T + lane + 64];
    }

    int idx = lastTag[b];
    const float bsc = out[(size_t)B * L + b];   // score at time 1023, tag idx
    float pp0 = bsc, pp1 = bsc;                 // "row at time r+1" (uniform at start)
    __syncthreads();                            // transT ready

    int r = 1022;

#define BODY(U_)                                                               \
    {                                                                          \
        const float c0_ = rp0[U_], c1_ = rp1[U_];                              \
        const float e0_ = re0[U_], e1_ = re1[U_];                              \
        const int pr = (r >= 8) ? (r - 8) : 0;                                 \
        rp0[U_] = prevws[pbase + (size_t)pr * T + lane];                       \
        rp1[U_] = prevws[pbase + (size_t)pr * T + lane + 64];                  \
        re0[U_] = emit[ebase + (size_t)(pr + 1) * T + lane];                   \
        re1[U_] = emit[ebase + (size_t)(pr + 1) * T + lane + 64];              \
        const int sl = idx & 63;                                               \
        const bool lo = idx < 64;                                              \
        const float bv  = __shfl(lo ? pp0 : pp1, sl);                          \
        const float ew0 = e0_ * w0, ew1 = e1_ * w1;                            \
        const float obs = __shfl(lo ? ew0 : ew1, sl);                          \
        const int xc = lane ^ (idx & 31);                                      \
        const float t0 = transT[idx * T + xc];                                 \
        const float t1 = transT[idx * T + 64 + xc];                            \
        const float s0 = (c0_ + obs) + t0;                                     \
        const float s1 = (c1_ + obs) + t1;                                     \
        const unsigned long long m0 = __ballot(s0 == bv);                      \
        const unsigned long long m1 = __ballot(s1 == bv);                      \
        idx = (m0 != 0ULL) ? __builtin_ctzll(m0)                               \
                           : 64 + __builtin_ctzll(m1);                         \
        if (lane == 0) out[obase + r] = (float)idx;                            \
        pp0 = c0_; pp1 = c1_;                                                  \
        --r;                                                                   \
    }

#pragma unroll 1
    for (int g = 0; g < 127; ++g) {    // 127 × 8 = 1016 iters: r = 1022 .. 7
        BODY(0) BODY(1) BODY(2) BODY(3) BODY(4) BODY(5) BODY(6) BODY(7)
    }
    // tail: r = 6 .. 0 (ring slots 0..6; prefetches clamp, values unused)
    BODY(0) BODY(1) BODY(2) BODY(3) BODY(4) BODY(5) BODY(6)
#undef BODY
}

// ===========================================================================
// FALLBACK PATH (R3 kernels, used when ws_size < 268 MB)
// ===========================================================================
__global__ __launch_bounds__(512, 4) void viterbi_fwd_slow(
    const float* __restrict__ emit, const float* __restrict__ trans,
    const float* __restrict__ w, float* __restrict__ out,
    u8* __restrict__ bps, int* __restrict__ lastTag)
{
    const int b   = blockIdx.x;
    const int tid = threadIdx.x;
    const int h   = tid & 3;
    const int j   = tid >> 2;
    const int hbase = h << 5;
    const bool lane0 = (h == 0);
    const int INF = 0x7fffffff;

    __shared__ __align__(16) float prevbuf[2 * T];
    __shared__ float swv[8];
    __shared__ int   swj[8];

    f2 tc2[16];
#pragma unroll
    for (int q = 0; q < 8; ++q) {
        f2 a, c;
        a.x = trans[(size_t)(hbase + 4 * q + 0) * T + j];
        a.y = trans[(size_t)(hbase + 4 * q + 1) * T + j];
        c.x = trans[(size_t)(hbase + 4 * q + 2) * T + j];
        c.y = trans[(size_t)(hbase + 4 * q + 3) * T + j];
        tc2[2 * q] = a; tc2[2 * q + 1] = c;
    }

    const float wj = w[j];
    const size_t ebase = (size_t)b * L * T;
    u8* bprow = bps + (size_t)b * NROWS * T;

    const char* prd = (const char*)prevbuf + 128 * h;
    char* pwr = (char*)prevbuf + 16 * ((j >> 2) ^ (j >> 5)) + 4 * (j & 3);

    const float e0 = emit[ebase + j] * wj;
    if (lane0) *(float*)pwr = e0;
    float myprev = e0;
    float raw_cur = emit[ebase + (size_t)T + j];
    int bidx_prev = 0;
    __syncthreads();

#define STEP(T_, ROFF_, WOFF_)                                                 \
    {                                                                          \
        const int t_ = (T_);                                                   \
        if (lane0 && t_ >= 2)                                                  \
            bprow[(size_t)(t_ - 2) * T + j] = (u8)bidx_prev;                   \
        const int tn_ = (t_ + 1 < L) ? (t_ + 1) : (L - 1);                     \
        const float raw_next_ = emit[ebase + (size_t)tn_ * T + j];             \
        const float obs_ = raw_cur * wj;                                       \
        f2 od_; od_.x = obs_; od_.y = obs_;                                    \
        f2 sv[16];                                                             \
        _Pragma("unroll")                                                      \
        for (int q = 0; q < 8; ++q) {                                          \
            const float4 p = *(const float4*)(prd + (ROFF_) + 16 * (q ^ h));   \
            f2 plo; plo.x = p.x; plo.y = p.y;                                  \
            f2 phi; phi.x = p.z; phi.y = p.w;                                  \
            sv[2 * q]     = (plo + od_) + tc2[2 * q];                          \
            sv[2 * q + 1] = (phi + od_) + tc2[2 * q + 1];                      \
        }                                                                      \
        float cm[4]; int loc[4];                                               \
        _Pragma("unroll")                                                      \
        for (int c = 0; c < 4; ++c) {                                          \
            const float s0 = sv[4 * c + 0].x, s1 = sv[4 * c + 0].y;            \
            const float s2 = sv[4 * c + 1].x, s3 = sv[4 * c + 1].y;            \
            const float s4 = sv[4 * c + 2].x, s5 = sv[4 * c + 2].y;            \
            const float s6 = sv[4 * c + 3].x, s7 = sv[4 * c + 3].y;            \
            const float m = M3(M3(s0, s1, s2), M3(s3, s4, s5),                 \
                               fmaxf(s6, s7));                                 \
            int k = 0;                                                         \
            k = (s7 == m) ? 7 : k; k = (s6 == m) ? 6 : k;                      \
            k = (s5 == m) ? 5 : k; k = (s4 == m) ? 4 : k;                      \
            k = (s3 == m) ? 3 : k; k = (s2 == m) ? 2 : k;                      \
            k = (s1 == m) ? 1 : k;                                             \
            cm[c] = m; loc[c] = 8 * c + k;                                     \
        }                                                                      \
        float bv = fmaxf(fmaxf(cm[0], cm[1]), fmaxf(cm[2], cm[3]));            \
        const int l0 = (cm[0] == bv) ? loc[0] : INF;                           \
        const int l1 = (cm[1] == bv) ? loc[1] : INF;                           \
        const int l2 = (cm[2] == bv) ? loc[2] : INF;                           \
        const int l3 = (cm[3] == bv) ? loc[3] : INF;                           \
        const int lm = min(min(min(l0, l1), l2), l3);                          \
        int gi = hbase + lm;                                                   \
        const float lv = bv;                                                   \
        bv = fmaxf(bv, __shfl_xor(bv, 1));                                     \
        bv = fmaxf(bv, __shfl_xor(bv, 2));                                     \
        int ii = (lv == bv) ? gi : INF;                                        \
        ii = min(ii, __shfl_xor(ii, 1));                                       \
        ii = min(ii, __shfl_xor(ii, 2));                                       \
        if (lane0) *(float*)(pwr + (WOFF_)) = bv;                              \
        myprev = bv;                                                           \
        bidx_prev = ii;                                                        \
        raw_cur = raw_next_;                                                   \
        __syncthreads();                                                       \
    }

    int t = 1;
    while (t + 1 < L) {
        STEP(t, 0, 512)
        STEP(t + 1, 512, 0)
        t += 2;
    }
    STEP(1023, 0, 512)
#undef STEP

    if (lane0) bprow[(size_t)(NROWS - 1) * T + j] = (u8)bidx_prev;

    float rv = myprev; int rj = j;
#pragma unroll
    for (int m = 4; m <= 32; m <<= 1) {
        const float pv = __shfl_xor(rv, m);
        const int   pj = __shfl_xor(rj, m);
        if (pv > rv || (pv == rv && pj < rj)) { rv = pv; rj = pj; }
    }
    if ((tid & 63) == 0) { swv[tid >> 6] = rv; swj[tid >> 6] = rj; }
    __syncthreads();
    if (tid == 0) {
        float fv = swv[0]; int fj = swj[0];
#pragma unroll
        for (int wv = 1; wv < 8; ++wv) {
            if (swv[wv] > fv || (swv[wv] == fv && swj[wv] < fj)) {
                fv = swv[wv]; fj = swj[wv];
            }
        }
        out[(size_t)B * L + b] = fv;
        out[(size_t)b * L + (L - 1)] = (float)fj;
        lastTag[b] = fj;
    }
}

__global__ __launch_bounds__(T) void segcomp(const u8* __restrict__ bps,
                                             u8* __restrict__ comp)
{
    const int s = blockIdx.x & (NSEG - 1);
    const int b = blockIdx.x >> 4;
    const int r0 = s * SEG;
    const int cnt = (NROWS - r0 < SEG) ? (NROWS - r0) : SEG;

    __shared__ __align__(16) u8 rows[SEG * T];
    const uint4* src = (const uint4*)(bps + ((size_t)b * NROWS + r0) * T);
    uint4* dst = (uint4*)rows;
    const int nvec = cnt * (T / 16);
    for (int k = threadIdx.x; k < nvec; k += T) dst[k] = src[k];
    __syncthreads();

    int x = threadIdx.x;
    for (int k = cnt - 1; k >= 0; --k) x = rows[k * T + x];
    comp[((size_t)b * NSEG + s) * T + threadIdx.x] = (u8)x;
}

__global__ void chainseg(const u8* __restrict__ comp,
                         const int* __restrict__ lastTag,
                         float* __restrict__ out)
{
    const int b = blockIdx.x * blockDim.x + threadIdx.x;
    if (b >= B) return;
    int e = lastTag[b];
#pragma unroll 1
    for (int s = NSEG - 1; s >= 0; --s) {
        e = comp[((size_t)b * NSEG + s) * T + e];
        out[(size_t)b * L + s * SEG] = (float)e;
    }
}

__global__ __launch_bounds__(T) void fillseg(const u8* __restrict__ bps,
                                             const int* __restrict__ lastTag,
                                             float* __restrict__ out)
{
    const int s = blockIdx.x & (NSEG - 1);
    const int b = blockIdx.x >> 4;
    const int r0 = s * SEG;
    const int cnt = (NROWS - r0 < SEG) ? (NROWS - r0) : SEG;

    __shared__ __align__(16) u8 rows[SEG * T];
    const uint4* src = (const uint4*)(bps + ((size_t)b * NROWS + r0) * T);
    uint4* dst = (uint4*)rows;
    const int nvec = cnt * (T / 16);
    for (int k = threadIdx.x; k < nvec; k += T) dst[k] = src[k];
    __syncthreads();

    if (threadIdx.x == 0) {
        int e = (s == NSEG - 1) ? lastTag[b]
                                : (int)out[(size_t)b * L + (size_t)(s + 1) * SEG];
        for (int k = cnt - 1; k >= 1; --k) {
            e = rows[k * T + e];
            out[(size_t)b * L + r0 + k] = (float)e;
        }
    }
}

// ---------------------------------------------------------------------------
extern "C" void kernel_launch(void* const* d_in, const int* in_sizes, int n_in,
                              void* d_out, int out_size, void* d_ws, size_t ws_size,
                              hipStream_t stream)
{
    const float* emit  = (const float*)d_in[0];
    const float* trans = (const float*)d_in[1];
    const float* w     = (const float*)d_in[2];
    float* out = (float*)d_out;

    const size_t prev_bytes = (size_t)B * NROWS * T * sizeof(float); // 268 MB
    const size_t need_fast  = prev_bytes + B * sizeof(int);

    if (ws_size >= need_fast) {
        float* prevws  = (float*)d_ws;
        int*   lastTag = (int*)((char*)d_ws + prev_bytes);
        viterbi_fwd_val<<<B, 512, 0, stream>>>(emit, trans, w, out, prevws, lastTag);
        backtrace<<<B, 64, 0, stream>>>(emit, trans, w, prevws, lastTag, out);
    } else {
        u8*  bps     = (u8*)d_ws;
        u8*  comp    = bps + (size_t)B * NROWS * T;
        int* lastTag = (int*)(comp + (size_t)B * NSEG * T);
        viterbi_fwd_slow<<<B, 512, 0, stream>>>(emit, trans, w, out, bps, lastTag);
        segcomp<<<B * NSEG, T, 0, stream>>>(bps, comp);
        chainseg<<<2, 256, 0, stream>>>(comp, lastTag, out);
        fillseg<<<B * NSEG, T, 0, stream>>>(bps, lastTag, out);
    }
}

// Round 6
// 861.762 us; speedup vs baseline: 1.9872x; 1.0184x over previous
//
#include <hip/hip_runtime.h>

#define B 512
#define L 1024
#define T 128
#define NROWS (L - 1)   /* 1023 */
#define SEG 64
#define NSEG 16

typedef unsigned char u8;
typedef float f2 __attribute__((ext_vector_type(2)));

#if __has_builtin(__builtin_elementwise_max)
#define MAX2(a, b) __builtin_elementwise_max((a), (b))
#else
static __device__ __forceinline__ f2 max2_(f2 a, f2 b) {
    f2 r; r.x = fmaxf(a.x, b.x); r.y = fmaxf(a.y, b.y); return r;
}
#define MAX2(a, b) max2_((a), (b))
#endif
#define M3(a, b, c) fmaxf(fmaxf((a), (b)), (c))

// Packed fp32 add (VOP3P, gfx90a+/CDNA4). Elementwise IEEE f32 add —
// bitwise identical to two v_add_f32.
static __device__ __forceinline__ f2 pkadd(f2 a, f2 b) {
    f2 d;
    asm("v_pk_add_f32 %0, %1, %2" : "=v"(d) : "v"(a), "v"(b));
    return d;
}
// 3-input max (VOP3). Pure selection — bitwise-safe for finite values.
static __device__ __forceinline__ float mx3(float a, float b, float c) {
    float d;
    asm("v_max3_f32 %0, %1, %2, %3" : "=v"(d) : "v"(a), "v"(b), "v"(c));
    return d;
}

// barrier WITHOUT vmcnt(0) drain: LDS visibility only (m201-verified pattern).
#define BAR()                                                  \
    do {                                                       \
        asm volatile("s_waitcnt lgkmcnt(0)" ::: "memory");     \
        __builtin_amdgcn_s_barrier();                          \
        asm volatile("" ::: "memory");                         \
    } while (0)

// ===========================================================================
// FAST PATH (needs ~268 MB workspace)
// ===========================================================================

// ---------------------------------------------------------------------------
// Forward, VALUES ONLY. v_pk_add_f32 + v_max3_f32 tree.
// Exact: s = (prev[i] + obs[j]) + trans[i][j]; max = selection (order-free).
// ---------------------------------------------------------------------------
__global__ __launch_bounds__(512, 4) void viterbi_fwd_val(
    const float* __restrict__ emit, const float* __restrict__ trans,
    const float* __restrict__ w, float* __restrict__ out,
    float* __restrict__ prevws, int* __restrict__ lastTag)
{
    const int b   = blockIdx.x;
    const int tid = threadIdx.x;
    const int h   = tid & 3;
    const int j   = tid >> 2;
    const int hbase = h << 5;
    const bool lane0 = (h == 0);

    __shared__ __align__(16) float prevbuf[2 * T];
    __shared__ float swv[8];
    __shared__ int   swj[8];

    f2 tc2[16];
#pragma unroll
    for (int q = 0; q < 8; ++q) {
        f2 a, c;
        a.x = trans[(size_t)(hbase + 4 * q + 0) * T + j];
        a.y = trans[(size_t)(hbase + 4 * q + 1) * T + j];
        c.x = trans[(size_t)(hbase + 4 * q + 2) * T + j];
        c.y = trans[(size_t)(hbase + 4 * q + 3) * T + j];
        tc2[2 * q] = a; tc2[2 * q + 1] = c;
    }

    const float wj = w[j];
    const size_t ebase = (size_t)b * L * T;
    float* prow = prevws + (size_t)b * NROWS * T;

    const char* prd = (const char*)prevbuf + 128 * h;
    char* pwr = (char*)prevbuf + 16 * ((j >> 2) ^ (j >> 5)) + 4 * (j & 3);

    const float e0 = emit[ebase + j] * wj;
    if (lane0) *(float*)pwr = e0;
    if (h == 1) prow[j] = e0;                       // prev row 0
    float myprev = e0;
    float r_c = emit[ebase + (size_t)T + j];        // row 1
    float r_1 = emit[ebase + (size_t)2 * T + j];    // row 2
    float bv_prev = 0.0f;
    BAR();

#define SVX(K_) ((K_ & 1) ? sv[(K_) >> 1].y : sv[(K_) >> 1].x)
#define STEP(T_, ROFF_, WOFF_)                                                 \
    {                                                                          \
        const int t_ = (T_);                                                   \
        if (h == 1 && t_ >= 2)                                                 \
            prow[(size_t)(t_ - 1) * T + j] = bv_prev;                          \
        const int tn_ = (t_ + 2 < L) ? (t_ + 2) : (L - 1);                     \
        const float r_2 = emit[ebase + (size_t)tn_ * T + j];                   \
        const float obs_ = r_c * wj;                                           \
        f2 od_; od_.x = obs_; od_.y = obs_;                                    \
        f2 sv[16];                                                             \
        _Pragma("unroll")                                                      \
        for (int q = 0; q < 8; ++q) {                                          \
            const float4 p = *(const float4*)(prd + (ROFF_) + 16 * (q ^ h));   \
            f2 plo; plo.x = p.x; plo.y = p.y;                                  \
            f2 phi; phi.x = p.z; phi.y = p.w;                                  \
            sv[2 * q]     = pkadd(pkadd(plo, od_), tc2[2 * q]);                \
            sv[2 * q + 1] = pkadd(pkadd(phi, od_), tc2[2 * q + 1]);            \
        }                                                                      \
        const float m0 = mx3(SVX(0),  SVX(1),  SVX(2));                        \
        const float m1 = mx3(SVX(3),  SVX(4),  SVX(5));                        \
        const float m2 = mx3(SVX(6),  SVX(7),  SVX(8));                        \
        const float m3 = mx3(SVX(9),  SVX(10), SVX(11));                       \
        const float m4 = mx3(SVX(12), SVX(13), SVX(14));                       \
        const float m5 = mx3(SVX(15), SVX(16), SVX(17));                       \
        const float m6 = mx3(SVX(18), SVX(19), SVX(20));                       \
        const float m7 = mx3(SVX(21), SVX(22), SVX(23));                       \
        const float m8 = mx3(SVX(24), SVX(25), SVX(26));                       \
        const float m9 = mx3(SVX(27), SVX(28), SVX(29));                       \
        const float m10 = fmaxf(SVX(30), SVX(31));                             \
        const float n0 = mx3(m0, m1, m2);                                      \
        const float n1 = mx3(m3, m4, m5);                                      \
        const float n2 = mx3(m6, m7, m8);                                      \
        const float n3 = fmaxf(m9, m10);                                       \
        float bv = fmaxf(mx3(n0, n1, n2), n3);                                 \
        bv = fmaxf(bv, __shfl_xor(bv, 1));                                     \
        bv = fmaxf(bv, __shfl_xor(bv, 2));                                     \
        if (lane0) *(float*)(pwr + (WOFF_)) = bv;                              \
        myprev = bv;                                                           \
        bv_prev = bv;                                                          \
        r_c = r_1; r_1 = r_2;                                                  \
        BAR();                                                                 \
    }

    int t = 1;
    while (t + 1 < L) {
        STEP(t, 0, 512)
        STEP(t + 1, 512, 0)
        t += 2;
    }
    STEP(1023, 0, 512)
#undef STEP
#undef SVX

    float rv = myprev; int rj = j;
#pragma unroll
    for (int m = 4; m <= 32; m <<= 1) {
        const float pv = __shfl_xor(rv, m);
        const int   pj = __shfl_xor(rj, m);
        if (pv > rv || (pv == rv && pj < rj)) { rv = pv; rj = pj; }
    }
    if ((tid & 63) == 0) { swv[tid >> 6] = rv; swj[tid >> 6] = rj; }
    __syncthreads();
    if (tid == 0) {
        float fv = swv[0]; int fj = swj[0];
#pragma unroll
        for (int wv = 1; wv < 8; ++wv) {
            if (swv[wv] > fv || (swv[wv] == fv && swj[wv] < fj)) {
                fv = swv[wv]; fj = swj[wv];
            }
        }
        out[(size_t)B * L + b] = fv;
        out[(size_t)b * L + (L - 1)] = (float)fj;
        lastTag[b] = fj;
    }
}

// ---------------------------------------------------------------------------
// Backtrace v2 (unchanged from R5 — measured ~117 µs, absmax 0).
// ---------------------------------------------------------------------------
__global__ __launch_bounds__(64, 1) void backtrace(
    const float* __restrict__ emit, const float* __restrict__ trans,
    const float* __restrict__ w, const float* __restrict__ prevws,
    const int* __restrict__ lastTag, float* __restrict__ out)
{
    const int b = blockIdx.x;
    const int lane = threadIdx.x;
    __shared__ float transT[T * T];   // 64 KB

    // stage transposed + swizzled: transT[j][i ^ (j&31)] = trans[i][j]
#pragma unroll 4
    for (int it = 0; it < (T * T) / 64; ++it) {
        const int k = it * 64 + lane;
        const int i = k >> 7, jj = k & 127;
        transT[jj * T + (i ^ (jj & 31))] = trans[k];
    }

    const float w0 = w[lane], w1 = w[lane + 64];
    const size_t pbase = (size_t)b * NROWS * T;
    const size_t ebase = (size_t)b * L * T;
    const size_t obase = (size_t)b * L;

    float rp0[8], rp1[8], re0[8], re1[8];
#pragma unroll
    for (int k = 0; k < 8; ++k) {
        rp0[k] = prevws[pbase + (size_t)(1022 - k) * T + lane];
        rp1[k] = prevws[pbase + (size_t)(1022 - k) * T + lane + 64];
        re0[k] = emit[ebase + (size_t)(1023 - k) * T + lane];
        re1[k] = emit[ebase + (size_t)(1023 - k) * T + lane + 64];
    }

    int idx = lastTag[b];
    const float bsc = out[(size_t)B * L + b];
    float pp0 = bsc, pp1 = bsc;
    __syncthreads();

    int r = 1022;

#define BODY(U_)                                                               \
    {                                                                          \
        const float c0_ = rp0[U_], c1_ = rp1[U_];                              \
        const float e0_ = re0[U_], e1_ = re1[U_];                              \
        const int pr = (r >= 8) ? (r - 8) : 0;                                 \
        rp0[U_] = prevws[pbase + (size_t)pr * T + lane];                       \
        rp1[U_] = prevws[pbase + (size_t)pr * T + lane + 64];                  \
        re0[U_] = emit[ebase + (size_t)(pr + 1) * T + lane];                   \
        re1[U_] = emit[ebase + (size_t)(pr + 1) * T + lane + 64];              \
        const int sl = idx & 63;                                               \
        const bool lo = idx < 64;                                              \
        const float bv  = __shfl(lo ? pp0 : pp1, sl);                          \
        const float ew0 = e0_ * w0, ew1 = e1_ * w1;                            \
        const float obs = __shfl(lo ? ew0 : ew1, sl);                          \
        const int xc = lane ^ (idx & 31);                                      \
        const float t0 = transT[idx * T + xc];                                 \
        const float t1 = transT[idx * T + 64 + xc];                            \
        const float s0 = (c0_ + obs) + t0;                                     \
        const float s1 = (c1_ + obs) + t1;                                     \
        const unsigned long long m0 = __ballot(s0 == bv);                      \
        const unsigned long long m1 = __ballot(s1 == bv);                      \
        idx = (m0 != 0ULL) ? __builtin_ctzll(m0)                               \
                           : 64 + __builtin_ctzll(m1);                         \
        if (lane == 0) out[obase + r] = (float)idx;                            \
        pp0 = c0_; pp1 = c1_;                                                  \
        --r;                                                                   \
    }

#pragma unroll 1
    for (int g = 0; g < 127; ++g) {    // 127 × 8 = 1016 iters: r = 1022 .. 7
        BODY(0) BODY(1) BODY(2) BODY(3) BODY(4) BODY(5) BODY(6) BODY(7)
    }
    BODY(0) BODY(1) BODY(2) BODY(3) BODY(4) BODY(5) BODY(6)
#undef BODY
}

// ===========================================================================
// FALLBACK PATH (R3 kernels, used when ws_size < 268 MB)
// ===========================================================================
__global__ __launch_bounds__(512, 4) void viterbi_fwd_slow(
    const float* __restrict__ emit, const float* __restrict__ trans,
    const float* __restrict__ w, float* __restrict__ out,
    u8* __restrict__ bps, int* __restrict__ lastTag)
{
    const int b   = blockIdx.x;
    const int tid = threadIdx.x;
    const int h   = tid & 3;
    const int j   = tid >> 2;
    const int hbase = h << 5;
    const bool lane0 = (h == 0);
    const int INF = 0x7fffffff;

    __shared__ __align__(16) float prevbuf[2 * T];
    __shared__ float swv[8];
    __shared__ int   swj[8];

    f2 tc2[16];
#pragma unroll
    for (int q = 0; q < 8; ++q) {
        f2 a, c;
        a.x = trans[(size_t)(hbase + 4 * q + 0) * T + j];
        a.y = trans[(size_t)(hbase + 4 * q + 1) * T + j];
        c.x = trans[(size_t)(hbase + 4 * q + 2) * T + j];
        c.y = trans[(size_t)(hbase + 4 * q + 3) * T + j];
        tc2[2 * q] = a; tc2[2 * q + 1] = c;
    }

    const float wj = w[j];
    const size_t ebase = (size_t)b * L * T;
    u8* bprow = bps + (size_t)b * NROWS * T;

    const char* prd = (const char*)prevbuf + 128 * h;
    char* pwr = (char*)prevbuf + 16 * ((j >> 2) ^ (j >> 5)) + 4 * (j & 3);

    const float e0 = emit[ebase + j] * wj;
    if (lane0) *(float*)pwr = e0;
    float myprev = e0;
    float raw_cur = emit[ebase + (size_t)T + j];
    int bidx_prev = 0;
    __syncthreads();

#define STEP(T_, ROFF_, WOFF_)                                                 \
    {                                                                          \
        const int t_ = (T_);                                                   \
        if (lane0 && t_ >= 2)                                                  \
            bprow[(size_t)(t_ - 2) * T + j] = (u8)bidx_prev;                   \
        const int tn_ = (t_ + 1 < L) ? (t_ + 1) : (L - 1);                     \
        const float raw_next_ = emit[ebase + (size_t)tn_ * T + j];             \
        const float obs_ = raw_cur * wj;                                       \
        f2 od_; od_.x = obs_; od_.y = obs_;                                    \
        f2 sv[16];                                                             \
        _Pragma("unroll")                                                      \
        for (int q = 0; q < 8; ++q) {                                          \
            const float4 p = *(const float4*)(prd + (ROFF_) + 16 * (q ^ h));   \
            f2 plo; plo.x = p.x; plo.y = p.y;                                  \
            f2 phi; phi.x = p.z; phi.y = p.w;                                  \
            sv[2 * q]     = (plo + od_) + tc2[2 * q];                          \
            sv[2 * q + 1] = (phi + od_) + tc2[2 * q + 1];                      \
        }                                                                      \
        float cm[4]; int loc[4];                                               \
        _Pragma("unroll")                                                      \
        for (int c = 0; c < 4; ++c) {                                          \
            const float s0 = sv[4 * c + 0].x, s1 = sv[4 * c + 0].y;            \
            const float s2 = sv[4 * c + 1].x, s3 = sv[4 * c + 1].y;            \
            const float s4 = sv[4 * c + 2].x, s5 = sv[4 * c + 2].y;            \
            const float s6 = sv[4 * c + 3].x, s7 = sv[4 * c + 3].y;            \
            const float m = M3(M3(s0, s1, s2), M3(s3, s4, s5),                 \
                               fmaxf(s6, s7));                                 \
            int k = 0;                                                         \
            k = (s7 == m) ? 7 : k; k = (s6 == m) ? 6 : k;                      \
            k = (s5 == m) ? 5 : k; k = (s4 == m) ? 4 : k;                      \
            k = (s3 == m) ? 3 : k; k = (s2 == m) ? 2 : k;                      \
            k = (s1 == m) ? 1 : k;                                             \
            cm[c] = m; loc[c] = 8 * c + k;                                     \
        }                                                                      \
        float bv = fmaxf(fmaxf(cm[0], cm[1]), fmaxf(cm[2], cm[3]));            \
        const int l0 = (cm[0] == bv) ? loc[0] : INF;                           \
        const int l1 = (cm[1] == bv) ? loc[1] : INF;                           \
        const int l2 = (cm[2] == bv) ? loc[2] : INF;                           \
        const int l3 = (cm[3] == bv) ? loc[3] : INF;                           \
        const int lm = min(min(min(l0, l1), l2), l3);                          \
        int gi = hbase + lm;                                                   \
        const float lv = bv;                                                   \
        bv = fmaxf(bv, __shfl_xor(bv, 1));                                     \
        bv = fmaxf(bv, __shfl_xor(bv, 2));                                     \
        int ii = (lv == bv) ? gi : INF;                                        \
        ii = min(ii, __shfl_xor(ii, 1));                                       \
        ii = min(ii, __shfl_xor(ii, 2));                                       \
        if (lane0) *(float*)(pwr + (WOFF_)) = bv;                              \
        myprev = bv;                                                           \
        bidx_prev = ii;                                                        \
        raw_cur = raw_next_;                                                   \
        __syncthreads();                                                       \
    }

    int t = 1;
    while (t + 1 < L) {
        STEP(t, 0, 512)
        STEP(t + 1, 512, 0)
        t += 2;
    }
    STEP(1023, 0, 512)
#undef STEP

    if (lane0) bprow[(size_t)(NROWS - 1) * T + j] = (u8)bidx_prev;

    float rv = myprev; int rj = j;
#pragma unroll
    for (int m = 4; m <= 32; m <<= 1) {
        const float pv = __shfl_xor(rv, m);
        const int   pj = __shfl_xor(rj, m);
        if (pv > rv || (pv == rv && pj < rj)) { rv = pv; rj = pj; }
    }
    if ((tid & 63) == 0) { swv[tid >> 6] = rv; swj[tid >> 6] = rj; }
    __syncthreads();
    if (tid == 0) {
        float fv = swv[0]; int fj = swj[0];
#pragma unroll
        for (int wv = 1; wv < 8; ++wv) {
            if (swv[wv] > fv || (swv[wv] == fv && swj[wv] < fj)) {
                fv = swv[wv]; fj = swj[wv];
            }
        }
        out[(size_t)B * L + b] = fv;
        out[(size_t)b * L + (L - 1)] = (float)fj;
        lastTag[b] = fj;
    }
}

__global__ __launch_bounds__(T) void segcomp(const u8* __restrict__ bps,
                                             u8* __restrict__ comp)
{
    const int s = blockIdx.x & (NSEG - 1);
    const int b = blockIdx.x >> 4;
    const int r0 = s * SEG;
    const int cnt = (NROWS - r0 < SEG) ? (NROWS - r0) : SEG;

    __shared__ __align__(16) u8 rows[SEG * T];
    const uint4* src = (const uint4*)(bps + ((size_t)b * NROWS + r0) * T);
    uint4* dst = (uint4*)rows;
    const int nvec = cnt * (T / 16);
    for (int k = threadIdx.x; k < nvec; k += T) dst[k] = src[k];
    __syncthreads();

    int x = threadIdx.x;
    for (int k = cnt - 1; k >= 0; --k) x = rows[k * T + x];
    comp[((size_t)b * NSEG + s) * T + threadIdx.x] = (u8)x;
}

__global__ void chainseg(const u8* __restrict__ comp,
                         const int* __restrict__ lastTag,
                         float* __restrict__ out)
{
    const int b = blockIdx.x * blockDim.x + threadIdx.x;
    if (b >= B) return;
    int e = lastTag[b];
#pragma unroll 1
    for (int s = NSEG - 1; s >= 0; --s) {
        e = comp[((size_t)b * NSEG + s) * T + e];
        out[(size_t)b * L + s * SEG] = (float)e;
    }
}

__global__ __launch_bounds__(T) void fillseg(const u8* __restrict__ bps,
                                             const int* __restrict__ lastTag,
                                             float* __restrict__ out)
{
    const int s = blockIdx.x & (NSEG - 1);
    const int b = blockIdx.x >> 4;
    const int r0 = s * SEG;
    const int cnt = (NROWS - r0 < SEG) ? (NROWS - r0) : SEG;

    __shared__ __align__(16) u8 rows[SEG * T];
    const uint4* src = (const uint4*)(bps + ((size_t)b * NROWS + r0) * T);
    uint4* dst = (uint4*)rows;
    const int nvec = cnt * (T / 16);
    for (int k = threadIdx.x; k < nvec; k += T) dst[k] = src[k];
    __syncthreads();

    if (threadIdx.x == 0) {
        int e = (s == NSEG - 1) ? lastTag[b]
                                : (int)out[(size_t)b * L + (size_t)(s + 1) * SEG];
        for (int k = cnt - 1; k >= 1; --k) {
            e = rows[k * T + e];
            out[(size_t)b * L + r0 + k] = (float)e;
        }
    }
}

// ---------------------------------------------------------------------------
extern "C" void kernel_launch(void* const* d_in, const int* in_sizes, int n_in,
                              void* d_out, int out_size, void* d_ws, size_t ws_size,
                              hipStream_t stream)
{
    const float* emit  = (const float*)d_in[0];
    const float* trans = (const float*)d_in[1];
    const float* w     = (const float*)d_in[2];
    float* out = (float*)d_out;

    const size_t prev_bytes = (size_t)B * NROWS * T * sizeof(float); // 268 MB
    const size_t need_fast  = prev_bytes + B * sizeof(int);

    if (ws_size >= need_fast) {
        float* prevws  = (float*)d_ws;
        int*   lastTag = (int*)((char*)d_ws + prev_bytes);
        viterbi_fwd_val<<<B, 512, 0, stream>>>(emit, trans, w, out, prevws, lastTag);
        backtrace<<<B, 64, 0, stream>>>(emit, trans, w, prevws, lastTag, out);
    } else {
        u8*  bps     = (u8*)d_ws;
        u8*  comp    = bps + (size_t)B * NROWS * T;
        int* lastTag = (int*)(comp + (size_t)B * NSEG * T);
        viterbi_fwd_slow<<<B, 512, 0, stream>>>(emit, trans, w, out, bps, lastTag);
        segcomp<<<B * NSEG, T, 0, stream>>>(bps, comp);
        chainseg<<<2, 256, 0, stream>>>(comp, lastTag, out);
        fillseg<<<B * NSEG, T, 0, stream>>>(bps, lastTag, out);
    }
}